// Round 18
// baseline (113.574 us; speedup 1.0000x reference)
//
#include <hip/hip_runtime.h>
#include <math.h>

// ChamferLoss: pred [32,4096,3] f32, gt [32,4096,3] f32 -> scalar f32.
//
// R22: SINGLE-PASS. R21 refuted the occupancy theory (grid 2x -> occupancy
// and wall unchanged; R5 same). Wall = fill 43.6 (harness) + main ~49 +
// tail. Within main: VALU 27us, MFMA 13.5us busy. Single-pass computes ONE
// matrix C[gt][pred] per batch and folds BOTH directions from it (row-mins
// = chamfer1, col-mins = chamfer2): MFMA busy halves to 6.75us at equal
// fold VALU (~2 ops/pair total either way). R13 measured this topology at
// main 43.2 even with separate prep + device-scope finisher. R22 adds all
// since-proven pieces: fused raw staging (R19), plain-store merges (R20/21,
// no atomics/fences/ws-init), (512,4) bounds (R20 taught: never (512,8) --
// unified VGPR/AGPR file spills).
//  - Block = (b, 256 gt rows), 8 waves = rw(4) x cq(2), 2 A-frags/wave,
//    sweeps all 4096 pred cols in 4 chunks of 32 staged tiles.
//  - gt-side: complete in-block; fold + cq-merge -> 256 floats to wsgt.
//  - pred-side: per-lane 32-row tmin -> LDS atomicMin sPmin[4096]
//    (R13-proven pattern, 0 bank conflicts) -> plain store block partials
//    to wspp[bx][4096].
//  - finish: pred = min over 16 panels + sqrt; gt = sqrt; sum -> out.
//
// Layouts (m74/m101-verified, 32x32x16 bf16):
//   A: row = lane&31, k = 8*(lane>>5)+i
//   B: col = lane&31, k = 8*(lane>>5)+i
//   C: col = lane&31, row = (reg&3) + 8*(reg>>2) + 4*(lane>>5)
// K-slot map (A = -2*gt split h/m, B = pred split h/m):
//   k0-5: Ah*(Bh,Bm)  k6-11: Am*(Bh,Bm)  k12-13: G2h,G2m*1  k14-15: 1*P2h,P2m
//   => acc = d2 directly. absmax 0.0 in R11-R17, R19-R21.

typedef short short8 __attribute__((ext_vector_type(8)));
typedef float f32x16 __attribute__((ext_vector_type(16)));
typedef unsigned int uint;

#define NPTS  4096
#define TPBM  512           // 8 waves = rw(4) x cq(2)
#define TPBP  256
#define NPANEL 16           // 256-row gt panels per batch
#define GRID_MAIN (32 * NPANEL)              // 512
#define CHT   16            // tiles per cq per chunk (32 staged total = 32KB)
#define NCH   4             // 64 tiles per cq
#define ONEB ((short)0x3F80)                 // bf16 1.0

// ---- bf16 split helpers (RNE) ----
__device__ __forceinline__ unsigned short bf16h(float f) {
    uint u = __float_as_uint(f);
    uint r = u + 0x7FFFu + ((u >> 16) & 1u);
    return (unsigned short)(r >> 16);
}
__device__ __forceinline__ float bf16f(unsigned short h) {
    return __uint_as_float(((uint)h) << 16);
}
struct Split2 { unsigned short h, m; };
__device__ __forceinline__ Split2 split2(float x) {
    Split2 s;
    s.h = bf16h(x);
    s.m = bf16h(x - bf16f(s.h));
    return s;
}

// ---- main: block = (batch, 256 gt rows) x all 4096 pred cols ----
__global__ __launch_bounds__(TPBM, 4) void chamfer_mfma(
    const float* __restrict__ pred,
    const float* __restrict__ gt,
    float* __restrict__ wsgt,     // [512][256] gt row-mins (complete)
    float* __restrict__ wspp)     // [512][4096] pred col-min block partials
{
    const int bx    = blockIdx.x;      // 512 = b(32) x panel(16)
    const int b     = bx >> 4;
    const int panel = bx & 15;
    const int tid   = threadIdx.x;
    const int lane  = tid & 63, wid = tid >> 6;
    const int rw    = wid >> 1;        // 0..3: 64-row group
    const int cq    = wid & 1;         // 0..1: 2048-col half
    const int c31   = lane & 31, half = lane >> 5;

    __shared__ short8 sB[2 * CHT * 64];   // 32 KB: [cq][t][lane]
    __shared__ uint   sPmin[NPTS];        // 16 KB: pred col-mins (uint-ordered)
    __shared__ float  sred[256 * 2];      // 2 KB: gt rows x cq

    const float* qsrc = gt   + (size_t)b * NPTS * 3;   // A side: gt rows
    const float* tsrc = pred + (size_t)b * NPTS * 3;   // B side: pred cols

    for (int c = tid; c < NPTS; c += TPBM) sPmin[c] = 0x7F7FFFFFu;

    // 2 A-frags: rows panel*256 + rw*64 + fr*32 + c31; -2*coords, g2 baked.
    short8 afr[2];
    float gm[2][16];
#pragma unroll
    for (int fr = 0; fr < 2; ++fr) {
        const int row = panel * 256 + rw * 64 + fr * 32 + c31;
        const float* ap = qsrc + (size_t)row * 3;
        float x = ap[0], y = ap[1], z = ap[2];
        Split2 X = split2(-2.0f*x), Y = split2(-2.0f*y), Z = split2(-2.0f*z);
        Split2 G2 = split2(fmaf(x, x, fmaf(y, y, z * z)));
        short8 a;
        if (half == 0) {
            a[0]=(short)X.h; a[1]=(short)Y.h; a[2]=(short)Z.h;
            a[3]=(short)X.h; a[4]=(short)Y.h; a[5]=(short)Z.h;
            a[6]=(short)X.m; a[7]=(short)Y.m;
        } else {
            a[0]=(short)Z.m; a[1]=(short)X.m; a[2]=(short)Y.m; a[3]=(short)Z.m;
            a[4]=(short)G2.h; a[5]=(short)G2.m; a[6]=ONEB; a[7]=ONEB;
        }
        afr[fr] = a;
#pragma unroll
        for (int r = 0; r < 16; ++r) gm[fr][r] = 1e30f;
    }

    const f32x16 zero = {0.f,0.f,0.f,0.f,0.f,0.f,0.f,0.f,
                         0.f,0.f,0.f,0.f,0.f,0.f,0.f,0.f};

    // Fused raw staging (R19): entry u -> ucq = u>>10, ut = (u>>6)&15,
    // ul = u&63; tile = ucq*64 + ch*CHT + ut; point = tile*32 + (ul&31).
    float rx[4], ry[4], rz[4];
#pragma unroll
    for (int ps = 0; ps < 4; ++ps) {
        const int u  = ps * TPBM + tid;
        const int pt = (((u >> 10) * 64) + ((u >> 6) & 15)) * 32 + (u & 31);
        const float* p = tsrc + (size_t)pt * 3;
        rx[ps] = p[0]; ry[ps] = p[1]; rz[ps] = p[2];
    }

    for (int ch = 0; ch < NCH; ++ch) {
        __syncthreads();   // prior chunk's reads done; ch=0: sPmin init done
#pragma unroll
        for (int ps = 0; ps < 4; ++ps) {
            const int u = ps * TPBM + tid;
            float x = rx[ps], y = ry[ps], z = rz[ps];
            Split2 X = split2(x), Y = split2(y), Z = split2(z);
            short8 f;
            if (((u >> 5) & 1) == 0) {
                f[0]=(short)X.h; f[1]=(short)Y.h; f[2]=(short)Z.h;
                f[3]=(short)X.m; f[4]=(short)Y.m; f[5]=(short)Z.m;
                f[6]=(short)X.h; f[7]=(short)Y.h;
            } else {
                Split2 P2 = split2(fmaf(x, x, fmaf(y, y, z * z)));
                f[0]=(short)Z.h; f[1]=(short)X.m; f[2]=(short)Y.m;
                f[3]=(short)Z.m; f[4]=ONEB; f[5]=ONEB;
                f[6]=(short)P2.h; f[7]=(short)P2.m;
            }
            sB[u] = f;
        }
        __syncthreads();   // sB visible

        const int chn = (ch + 1 < NCH) ? ch + 1 : ch;   // clamp: no overread
#pragma unroll
        for (int ps = 0; ps < 4; ++ps) {
            const int u  = ps * TPBM + tid;
            const int pt = (((u >> 10) * 64) + chn * CHT + ((u >> 6) & 15)) * 32
                           + (u & 31);
            const float* p = tsrc + (size_t)pt * 3;
            rx[ps] = p[0]; ry[ps] = p[1]; rz[ps] = p[2];
        }

        // 16 tiles per wave: 1 ds_read + 2 MFMA + 64 fmin + 1 LDS atomic
#pragma unroll 4
        for (int t = 0; t < CHT; ++t) {
            short8 bfr = sB[(cq * CHT + t) * 64 + lane];
            f32x16 a0 = __builtin_amdgcn_mfma_f32_32x32x16_bf16(
                afr[0], bfr, zero, 0, 0, 0);
            f32x16 a1 = __builtin_amdgcn_mfma_f32_32x32x16_bf16(
                afr[1], bfr, zero, 0, 0, 0);

            float tmin = 1e30f;
#pragma unroll
            for (int r = 0; r < 16; ++r) {
                gm[0][r] = fminf(gm[0][r], a0[r]);            // gt row-mins
                gm[1][r] = fminf(gm[1][r], a1[r]);
                tmin = fminf(tmin, fminf(a0[r], a1[r]));      // pred col-min
            }
            // lane's 32-row col-min -> LDS atomic folds halves + rw waves
            atomicMin(&sPmin[cq * 2048 + (ch * CHT + t) * 32 + c31],
                      __float_as_uint(fmaxf(tmin, 1e-12f)));
        }
    }
    __syncthreads();   // sPmin complete

    // pred-side: plain store of block partials (write-once, coalesced)
    float* wp = wspp + (size_t)bx * NPTS;
    for (int c = tid; c < NPTS; c += TPBM)
        wp[c] = __uint_as_float(sPmin[c]);

    // gt-side: fold row-mins across the 32 cols (c31 lanes, within half)
#pragma unroll
    for (int off = 1; off < 32; off <<= 1)
#pragma unroll
        for (int fr = 0; fr < 2; ++fr)
#pragma unroll
            for (int r = 0; r < 16; ++r)
                gm[fr][r] = fminf(gm[fr][r], __shfl_xor(gm[fr][r], off, 64));
    if (c31 == 0) {   // lanes 0 and 32 (half 0/1) hold disjoint rows
#pragma unroll
        for (int fr = 0; fr < 2; ++fr)
#pragma unroll
            for (int r = 0; r < 16; ++r)
                sred[(rw*64 + fr*32 + (r&3) + 8*(r>>2) + 4*half) * 2 + cq]
                    = gm[fr][r];
    }
    __syncthreads();

    if (tid < 256) {   // merge cq halves, plain store row-mins
        float v = fminf(sred[tid * 2], sred[tid * 2 + 1]);
        wsgt[(size_t)bx * 256 + tid] = v;
    }
}

// ---- finish: pred 16-panel merge + sqrt; gt sqrt; sum -> out[0] ----
__global__ __launch_bounds__(TPBP) void chamfer_finish(
    const float* __restrict__ wsgt, const float* __restrict__ wspp,
    float* __restrict__ out)
{
    __shared__ float swv[TPBP / 64];
    const int tid = threadIdx.x;
    float s = 0.0f;

    // pred side: 131072 (b,c) slots, 4 per thread; min over 16 panels
#pragma unroll
    for (int i = 0; i < 4; ++i) {
        const int slot = blockIdx.x * (TPBP * 4) + i * TPBP + tid;
        const int b = slot >> 12, c = slot & 4095;
        const float* base = wspp + ((size_t)b * 16) * NPTS + c;
        float v = 1e30f;
#pragma unroll
        for (int p = 0; p < 16; ++p) v = fminf(v, base[(size_t)p * NPTS]);
        s += sqrtf(fmaxf(v, 1e-12f));
    }
    // gt side: 131072 rows, 4 per thread (already complete mins)
#pragma unroll
    for (int i = 0; i < 4; ++i) {
        const int idx = blockIdx.x * (TPBP * 4) + i * TPBP + tid;
        s += sqrtf(fmaxf(wsgt[idx], 1e-12f));
    }

#pragma unroll
    for (int off = 32; off > 0; off >>= 1) s += __shfl_down(s, off, 64);
    const int wid = tid >> 6, lane = tid & 63;
    if (lane == 0) swv[wid] = s;
    __syncthreads();
    if (tid == 0) {
        float tot = swv[0] + swv[1] + swv[2] + swv[3];
        atomicAdd(out, tot * (1.0f / 131072.0f));
    }
}

extern "C" void kernel_launch(void* const* d_in, const int* in_sizes, int n_in,
                              void* d_out, int out_size, void* d_ws, size_t ws_size,
                              hipStream_t stream)
{
    const float* pred = (const float*)d_in[0];
    const float* gt   = (const float*)d_in[1];
    float* out        = (float*)d_out;

    // ws layout: [0,512K) wsgt (131072 f); [1M,9M) wspp (512x4096 f)
    float* wsgt = (float*)d_ws;
    float* wspp = (float*)((char*)d_ws + (1 << 20));

    hipMemsetAsync(d_out, 0, sizeof(float), stream);

    chamfer_mfma<<<dim3(GRID_MAIN), dim3(TPBM), 0, stream>>>(
        pred, gt, wsgt, wspp);
    chamfer_finish<<<dim3(131072 / (TPBP * 4)), dim3(TPBP), 0, stream>>>(
        wsgt, wspp, out);
}

// Round 19
// 97.550 us; speedup vs baseline: 1.1643x; 1.1643x over previous
//
#include <hip/hip_runtime.h>
#include <math.h>

// ChamferLoss: pred [32,4096,3] f32, gt [32,4096,3] f32 -> scalar f32.
//
// R23 = R19 EXACTLY (two-pass, fused raw staging, T14 async-stage, CHT=32,
// grid 512; total 97.8us best, main 48.7) + ONE change: the MFMA->fold
// dependency is software-pipelined (T15).
// Evidence: in every healthy variant VALUBusy+MfmaUtil ~ 85-90% of wall
// (R19 57+28, R21 54+27, R22 65+11) -> the matrix and vector pipes do NOT
// overlap: each fold consumes its MFMA's acc immediately, stalling the wave
// through the 32-cy matrix-pipe occupancy; barrier-synced waves can't cover
// each other (why occupancy was null twice, R5/R21). R22 also showed
// single-pass trades 7us MFMA for 12us of merge VALU -> two-pass stands.
// Pipeline: per tile t, issue MFMA_a0(t) -> fold a0(t-1) -> MFMA_a1(t) ->
// fold a1(t-1): each 32-cy MFMA dovetails a 16x2-cy fold. Rotating NAMED
// accumulators (rule #20: no runtime indexing); live regs ~110 < 128 cap.
// R20 lesson kept: (512,4) only -- (512,8) spills on the unified reg file.
//
// Layouts (m74/m101-verified, 32x32x16 bf16):
//   A: row = lane&31, k = 8*(lane>>5)+i
//   B: col = lane&31, k = 8*(lane>>5)+i
//   C: col = lane&31, row = (reg&3) + 8*(reg>>2) + 4*(lane>>5)
// K-slot map (A = -2*query split h/m, B = target split h/m):
//   k0-5: Ah*(Bh,Bm)  k6-11: Am*(Bh,Bm)  k12-13: Q2h,Q2m*1  k14-15: 1*T2h,T2m
//   => acc = d2 = q2 + t2 - 2*dot directly.  (absmax 0.0 in R11-R22)

typedef short short8 __attribute__((ext_vector_type(8)));
typedef float f32x16 __attribute__((ext_vector_type(16)));
typedef unsigned int uint;

#define NPTS  4096
#define TPBM  512           // 8 waves, each owns 64 rows (2 A-frags)
#define TPBP  256
#define NPANEL 8            // 512-row query panels
#define GRID_MAIN (2 * 32 * NPANEL)          // 512
#define CHT   32            // tiles per chunk (32 cols each) = 32KB staged
#define NCH   4             // 128 tiles total per (dir,batch)
#define ONEB ((short)0x3F80)                 // bf16 1.0

// ---- bf16 split helpers (RNE) ----
__device__ __forceinline__ unsigned short bf16h(float f) {
    uint u = __float_as_uint(f);
    uint r = u + 0x7FFFu + ((u >> 16) & 1u);
    return (unsigned short)(r >> 16);
}
__device__ __forceinline__ float bf16f(unsigned short h) {
    return __uint_as_float(((uint)h) << 16);
}
struct Split2 { unsigned short h, m; };
__device__ __forceinline__ Split2 split2(float x) {
    Split2 s;
    s.h = bf16h(x);
    s.m = bf16h(x - bf16f(s.h));
    return s;
}

// ---- main: block = (dir, batch, 512 query rows) x all 4096 target cols ----
__global__ __launch_bounds__(TPBM, 4) void chamfer_mfma(
    const float* __restrict__ pred,
    const float* __restrict__ gt,
    float* __restrict__ wsgt)
{
    const int bx    = blockIdx.x;      // 512 = dir(2) x b(32) x panel(8)
    const int dir   = bx >> 8;
    const int rem   = bx & 255;
    const int b     = rem >> 3;
    const int panel = rem & 7;
    const int tid   = threadIdx.x;
    const int lane  = tid & 63, wid = tid >> 6;
    const int c31   = lane & 31, half = lane >> 5;

    __shared__ short8 sB[CHT * 64];   // 32 KB, shared by all 8 waves
    __shared__ float  sw[8];

    // dir0: queries = gt rows, targets = pred; dir1: queries = pred, targets = gt
    const float* qsrc = (dir ? pred : gt) + (size_t)b * NPTS * 3;
    const float* tsrc = (dir ? gt : pred) + (size_t)b * NPTS * 3;

    // 2 A-frags: rows panel*512 + wid*64 + fr*32 + c31; -2*coords, q2 baked.
    short8 afr[2];
    float gm[2][16];
#pragma unroll
    for (int fr = 0; fr < 2; ++fr) {
        const int row = panel * 512 + wid * 64 + fr * 32 + c31;
        const float* ap = qsrc + (size_t)row * 3;
        float x = ap[0], y = ap[1], z = ap[2];
        Split2 X = split2(-2.0f*x), Y = split2(-2.0f*y), Z = split2(-2.0f*z);
        Split2 Q2 = split2(fmaf(x, x, fmaf(y, y, z * z)));
        short8 a;
        if (half == 0) {
            a[0]=(short)X.h; a[1]=(short)Y.h; a[2]=(short)Z.h;
            a[3]=(short)X.h; a[4]=(short)Y.h; a[5]=(short)Z.h;
            a[6]=(short)X.m; a[7]=(short)Y.m;
        } else {
            a[0]=(short)Z.m; a[1]=(short)X.m; a[2]=(short)Y.m; a[3]=(short)Z.m;
            a[4]=(short)Q2.h; a[5]=(short)Q2.m; a[6]=ONEB; a[7]=ONEB;
        }
        afr[fr] = a;
#pragma unroll
        for (int r = 0; r < 16; ++r) gm[fr][r] = 1e30f;
    }

    const f32x16 zero = {0.f,0.f,0.f,0.f,0.f,0.f,0.f,0.f,
                         0.f,0.f,0.f,0.f,0.f,0.f,0.f,0.f};

    // T14 async-stage, raw form: rx/ry/rz hold the NEXT chunk's coords.
    float rx[4], ry[4], rz[4];
#pragma unroll
    for (int ps = 0; ps < 4; ++ps) {
        const int u  = ps * TPBM + tid;
        const int pt = (u >> 6) * 32 + (u & 31);     // chunk 0
        const float* p = tsrc + (size_t)pt * 3;
        rx[ps] = p[0]; ry[ps] = p[1]; rz[ps] = p[2];
    }

    for (int ch = 0; ch < NCH; ++ch) {
        __syncthreads();   // prior chunk's reads done
        // build fragments in-register, write to LDS (fused prep)
#pragma unroll
        for (int ps = 0; ps < 4; ++ps) {
            const int u = ps * TPBM + tid;
            float x = rx[ps], y = ry[ps], z = rz[ps];
            Split2 X = split2(x), Y = split2(y), Z = split2(z);
            short8 f;
            if (((u >> 5) & 1) == 0) {
                f[0]=(short)X.h; f[1]=(short)Y.h; f[2]=(short)Z.h;
                f[3]=(short)X.m; f[4]=(short)Y.m; f[5]=(short)Z.m;
                f[6]=(short)X.h; f[7]=(short)Y.h;
            } else {
                Split2 T2 = split2(fmaf(x, x, fmaf(y, y, z * z)));
                f[0]=(short)Z.h; f[1]=(short)X.m; f[2]=(short)Y.m;
                f[3]=(short)Z.m; f[4]=ONEB; f[5]=ONEB;
                f[6]=(short)T2.h; f[7]=(short)T2.m;
            }
            sB[u] = f;
        }
        __syncthreads();   // sB visible

        const int chn = (ch + 1 < NCH) ? ch + 1 : ch;   // clamp: no overread
#pragma unroll
        for (int ps = 0; ps < 4; ++ps) {
            const int u  = ps * TPBM + tid;
            const int pt = (chn * CHT + (u >> 6)) * 32 + (u & 31);
            const float* p = tsrc + (size_t)pt * 3;
            rx[ps] = p[0]; ry[ps] = p[1]; rz[ps] = p[2];
        }

        // T15 software pipeline: MFMA(t) issues before fold(t-1) consumes.
        // Per iter: MFMA_a0(t) | fold a0(t-1) | MFMA_a1(t) | fold a1(t-1).
        {
            short8 b0 = sB[lane];
            f32x16 a0p = __builtin_amdgcn_mfma_f32_32x32x16_bf16(
                afr[0], b0, zero, 0, 0, 0);
            f32x16 a1p = __builtin_amdgcn_mfma_f32_32x32x16_bf16(
                afr[1], b0, zero, 0, 0, 0);
#pragma unroll 4
            for (int t = 1; t < CHT; ++t) {
                short8 bn = sB[t * 64 + lane];
                f32x16 a0n = __builtin_amdgcn_mfma_f32_32x32x16_bf16(
                    afr[0], bn, zero, 0, 0, 0);
#pragma unroll
                for (int r = 0; r < 16; ++r)
                    gm[0][r] = fminf(gm[0][r], a0p[r]);   // covers a0n's pipe
                f32x16 a1n = __builtin_amdgcn_mfma_f32_32x32x16_bf16(
                    afr[1], bn, zero, 0, 0, 0);
#pragma unroll
                for (int r = 0; r < 16; ++r)
                    gm[1][r] = fminf(gm[1][r], a1p[r]);   // covers a1n's pipe
                a0p = a0n; a1p = a1n;
            }
#pragma unroll
            for (int r = 0; r < 16; ++r) {                // epilogue folds
                gm[0][r] = fminf(gm[0][r], a0p[r]);
                gm[1][r] = fminf(gm[1][r], a1p[r]);
            }
        }
    }

    // Epilogue: fold row-mins across the 32 target-cols (c31 lanes).
#pragma unroll
    for (int off = 1; off < 32; off <<= 1)
#pragma unroll
        for (int fr = 0; fr < 2; ++fr)
#pragma unroll
            for (int r = 0; r < 16; ++r)
                gm[fr][r] = fminf(gm[fr][r], __shfl_xor(gm[fr][r], off, 64));

    // lanes 0 and 32 hold complete mins for 2x16 disjoint rows each
    float s = 0.0f;
    if (c31 == 0) {
#pragma unroll
        for (int fr = 0; fr < 2; ++fr)
#pragma unroll
            for (int r = 0; r < 16; ++r)
                s += sqrtf(fmaxf(gm[fr][r], 1e-12f));
    }
    s += __shfl_xor(s, 32, 64);   // combine halves
    if (lane == 0) sw[wid] = s;
    __syncthreads();
    if (tid == 0)
        wsgt[bx] = sw[0]+sw[1]+sw[2]+sw[3]+sw[4]+sw[5]+sw[6]+sw[7];
}

// ---- finish: one block sums the 512 per-block partials -> out[0] ----
__global__ __launch_bounds__(TPBP) void chamfer_finish(
    const float* __restrict__ wsgt, float* __restrict__ out)
{
    __shared__ float swv[TPBP / 64];
    const int tid = threadIdx.x;

    float s = 0.0f;
#pragma unroll
    for (int r = 0; r < GRID_MAIN / TPBP; ++r)
        s += wsgt[tid + r * TPBP];

#pragma unroll
    for (int off = 32; off > 0; off >>= 1) s += __shfl_down(s, off, 64);
    const int wid = tid >> 6, lane = tid & 63;
    if (lane == 0) swv[wid] = s;
    __syncthreads();
    if (tid == 0)
        out[0] = (swv[0] + swv[1] + swv[2] + swv[3]) * (1.0f / 131072.0f);
}

extern "C" void kernel_launch(void* const* d_in, const int* in_sizes, int n_in,
                              void* d_out, int out_size, void* d_ws, size_t ws_size,
                              hipStream_t stream)
{
    const float* pred = (const float*)d_in[0];
    const float* gt   = (const float*)d_in[1];
    float* out        = (float*)d_out;
    float* wsgt       = (float*)d_ws;   // 2KB of partials

    chamfer_mfma<<<dim3(GRID_MAIN), dim3(TPBM), 0, stream>>>(pred, gt, wsgt);
    chamfer_finish<<<dim3(1), dim3(TPBP), 0, stream>>>(wsgt, out);
}